// Round 1
// baseline (12160.547 us; speedup 1.0000x reference)
//
#include <hip/hip_runtime.h>
#include <stdint.h>

#define NPTS 8192
#define BATCH 2
#define KNN 20
#define BN_EPS 1e-5f

// ---------------------------------------------------------------------------
// transpose x [B,3,N] -> xt [B,N,4] (pad 4th chan with 0) + squared norms
// ---------------------------------------------------------------------------
__global__ __launch_bounds__(256) void k_xt(const float* __restrict__ x,
                                            float* __restrict__ xt,
                                            float* __restrict__ nrm) {
  int i = blockIdx.x * 256 + threadIdx.x;          // over B*N
  int b = i / NPTS, n = i % NPTS;
  float x0 = x[((size_t)b * 3 + 0) * NPTS + n];
  float x1 = x[((size_t)b * 3 + 1) * NPTS + n];
  float x2 = x[((size_t)b * 3 + 2) * NPTS + n];
  float4 v = make_float4(x0, x1, x2, 0.f);
  reinterpret_cast<float4*>(xt)[i] = v;
  // mimic np.sum(x*x) order: ((x0^2 + x1^2) + x2^2), no fma
  float s0 = x0 * x0, s1 = x1 * x1, s2 = x2 * x2;
  nrm[i] = (s0 + s1) + s2;
}

// ---------------------------------------------------------------------------
// squared norms of a channel-slice of Xcat: nrm[b*N+n] = sum_c X[(bN+n)*S+coff+c]^2
// ---------------------------------------------------------------------------
__global__ __launch_bounds__(256) void k_norms(const float* __restrict__ X,
                                               int S, int coff, int C,
                                               float* __restrict__ nrm) {
  int i = blockIdx.x * 256 + threadIdx.x;          // over B*N
  const float4* p = reinterpret_cast<const float4*>(&X[(size_t)i * S + coff]);
  float s = 0.f;
  for (int c4 = 0; c4 < (C >> 2); ++c4) {
    float4 v = p[c4];
    s = fmaf(v.x, v.x, s); s = fmaf(v.y, v.y, s);
    s = fmaf(v.z, v.z, s); s = fmaf(v.w, v.w, s);
  }
  nrm[i] = s;
}

// ---------------------------------------------------------------------------
// build stacked weights A2[2O][Cpad]: rows 0..O-1 = Wn, rows O..2O-1 = Wc-Wn
// (zero-pad c >= Creal; W is [O][2*Creal] row-major)
// ---------------------------------------------------------------------------
__global__ __launch_bounds__(256) void k_prep(const float* __restrict__ W,
                                              float* __restrict__ A2,
                                              int O, int Creal, int Cpad) {
  int i = blockIdx.x * 256 + threadIdx.x;
  if (i >= O * Cpad) return;
  int o = i / Cpad, c = i % Cpad;
  float wn = (c < Creal) ? W[(size_t)o * 2 * Creal + c] : 0.f;
  float wc = (c < Creal) ? W[(size_t)o * 2 * Creal + Creal + c] : 0.f;
  A2[(size_t)o * Cpad + c] = wn;
  A2[(size_t)(O + o) * Cpad + c] = wc - wn;
}

// ---------------------------------------------------------------------------
// KNN: for each row i, indices of the 20 smallest (xx_j - (2*dot - xx_i)),
// ties broken by smaller j (== jax.lax.top_k stable semantics on -dist^2).
// Block = 256 thr (4 waves) handles 16 rows; wave w owns rows [4w,4w+4),
// scans ALL j with lane = j-within-tile.
//
// Loop nest is c4-OUTER / row-INNER with per-row 4-part register accumulators:
// only one float4 of xj is live at a time (vs 32 in the row-outer variant,
// which overflowed the 108-VGPR budget and made the compiler rematerialize
// global loads of xj per row).  Accumulation order per row is unchanged
// (a0..a3 over ascending c4, then (a0+a1)+(a2+a3)) so distances are bitwise
// identical to the previous passing kernel.
// 16 rows/block -> 1024 blocks -> 4 blocks/CU (was 2) for latency hiding.
// ---------------------------------------------------------------------------
template <int C>
__global__ __launch_bounds__(256) void k_knn(const float* __restrict__ X,
                                             const float* __restrict__ nrm,
                                             int S, int coff,
                                             int* __restrict__ idxout) {
  constexpr int C4 = C / 4;
  constexpr int ROWS = 16;                 // rows per block, 4 per wave
  __shared__ __align__(16) float s_xi[ROWS * C];
  __shared__ float s_ni[ROWS];
  __shared__ unsigned long long s_list[ROWS * KNN];

  const int b = blockIdx.y;
  const int rowbase = blockIdx.x * ROWS;
  const int tid = threadIdx.x, wave = tid >> 6, lane = tid & 63;

  for (int v = tid; v < ROWS * KNN; v += 256) s_list[v] = ~0ull;
  for (int v = tid; v < ROWS * C; v += 256) {
    int r = v / C, c = v % C;
    s_xi[v] = X[(size_t)(b * NPTS + rowbase + r) * S + coff + c];
  }
  if (tid < ROWS) s_ni[tid] = nrm[b * NPTS + rowbase + tid];
  __syncthreads();

  const int r0 = wave * 4;
  for (int jt = 0; jt < NPTS; jt += 64) {
    const int j = jt + lane;
    const float4* xp =
        reinterpret_cast<const float4*>(&X[(size_t)(b * NPTS + j) * S + coff]);
    const float nj = nrm[b * NPTS + j];

    float a[4][4];
#pragma unroll
    for (int r = 0; r < 4; ++r)
      a[r][0] = a[r][1] = a[r][2] = a[r][3] = 0.f;

#pragma unroll
    for (int c4 = 0; c4 < C4; ++c4) {
      float4 xj = xp[c4];                          // 1 global dwordx4, once
#pragma unroll
      for (int r = 0; r < 4; ++r) {
        float4 v =
            *reinterpret_cast<const float4*>(&s_xi[(r0 + r) * C + 4 * c4]);
        a[r][0] = fmaf(v.x, xj.x, a[r][0]);
        a[r][1] = fmaf(v.y, xj.y, a[r][1]);
        a[r][2] = fmaf(v.z, xj.z, a[r][2]);
        a[r][3] = fmaf(v.w, xj.w, a[r][3]);
      }
    }

#pragma unroll
    for (int r = 0; r < 4; ++r) {
      float dot = (a[r][0] + a[r][1]) + (a[r][2] + a[r][3]);
      float t = fmaf(2.f, dot, -s_ni[r0 + r]);     // (-xx_i + 2*dot), ref order
      float d = nj - t;                            // ascending d == descending pd
      unsigned u = __float_as_uint(d);
      u ^= (unsigned)(((int)u) >> 31) | 0x80000000u;   // orderable float
      unsigned long long key = ((unsigned long long)u << 32) | (unsigned)j;

      unsigned long long* lp = &s_list[(r0 + r) * KNN];
      unsigned long long thr = lp[KNN - 1];            // broadcast read
      unsigned long long mask = __ballot(key < thr);
      while (mask) {
        int src = __ffsll((long long)mask) - 1;
        unsigned long long ck = __shfl(key, src);
        unsigned long long e = (lane < KNN) ? lp[lane] : ~0ull;
        unsigned long long ep = __shfl_up(e, 1);
        bool cc = ck < e;
        bool cp = (lane > 0) && (ck < ep);
        unsigned long long ne = cp ? ep : (cc ? ck : e);
        if (lane < KNN) lp[lane] = ne;
        thr = __shfl(ne, KNN - 1);
        if (lane == src) key = ~0ull;   // consumed
        mask = __ballot(key < thr);
      }
    }
  }
  // each wave owns its rows' lists: write indices (order within k irrelevant)
  if (lane < KNN) {
#pragma unroll
    for (int r = 0; r < 4; ++r)
      idxout[(size_t)(b * NPTS + rowbase + r0 + r) * KNN + lane] =
          (int)(s_list[(r0 + r) * KNN + lane] & 0xffffffffull);
  }
}

// ---------------------------------------------------------------------------
// per-point GEMM: Y[b,n,o] = sum_c A[o*C+c] * X[(b*N+n)*S+coff+c]
// 64 pts x 64 outs per block, K-chunks of 16 staged in LDS, 4x4 per thread.
// ---------------------------------------------------------------------------
__global__ __launch_bounds__(256) void k_gemm(const float* __restrict__ A,
                                              const float* __restrict__ X,
                                              float* __restrict__ Y,
                                              int S, int coff, int C, int O2) {
  __shared__ __align__(16) float sX[16 * 68];
  __shared__ __align__(16) float sA[16 * 68];
  const int b = blockIdx.z;
  const int nb = blockIdx.x * 64;
  const int ob = blockIdx.y * 64;
  const int tid = threadIdx.x, ty = tid >> 4, tx = tid & 15;
  float acc[4][4] = {};

  for (int kc = 0; kc < C; kc += 16) {
#pragma unroll
    for (int t = 0; t < 4; ++t) {
      int v = tid + t * 256;
      int p = v >> 4, k = v & 15;
      float xv = 0.f, av = 0.f;
      if (kc + k < C) {
        xv = X[(size_t)(b * NPTS + nb + p) * S + coff + kc + k];
        av = A[(size_t)(ob + p) * C + kc + k];
      }
      sX[k * 68 + p] = xv;
      sA[k * 68 + p] = av;
    }
    __syncthreads();
#pragma unroll
    for (int kk = 0; kk < 16; ++kk) {
      float4 xa = *reinterpret_cast<const float4*>(&sX[kk * 68 + ty * 4]);
      float4 wb = *reinterpret_cast<const float4*>(&sA[kk * 68 + tx * 4]);
      acc[0][0] = fmaf(xa.x, wb.x, acc[0][0]);
      acc[0][1] = fmaf(xa.x, wb.y, acc[0][1]);
      acc[0][2] = fmaf(xa.x, wb.z, acc[0][2]);
      acc[0][3] = fmaf(xa.x, wb.w, acc[0][3]);
      acc[1][0] = fmaf(xa.y, wb.x, acc[1][0]);
      acc[1][1] = fmaf(xa.y, wb.y, acc[1][1]);
      acc[1][2] = fmaf(xa.y, wb.z, acc[1][2]);
      acc[1][3] = fmaf(xa.y, wb.w, acc[1][3]);
      acc[2][0] = fmaf(xa.z, wb.x, acc[2][0]);
      acc[2][1] = fmaf(xa.z, wb.y, acc[2][1]);
      acc[2][2] = fmaf(xa.z, wb.z, acc[2][2]);
      acc[2][3] = fmaf(xa.z, wb.w, acc[2][3]);
      acc[3][0] = fmaf(xa.w, wb.x, acc[3][0]);
      acc[3][1] = fmaf(xa.w, wb.y, acc[3][1]);
      acc[3][2] = fmaf(xa.w, wb.z, acc[3][2]);
      acc[3][3] = fmaf(xa.w, wb.w, acc[3][3]);
    }
    __syncthreads();
  }
#pragma unroll
  for (int i = 0; i < 4; ++i) {
    float4 st = make_float4(acc[i][0], acc[i][1], acc[i][2], acc[i][3]);
    *reinterpret_cast<float4*>(
        &Y[(size_t)(b * NPTS + nb + ty * 4 + i) * O2 + ob + tx * 4]) = st;
  }
}

// ---------------------------------------------------------------------------
// gather + max-over-k + BN + LeakyReLU (monotone fold):
// out = leaky(a * ((a>=0 ? max_k : min_k) U[idx_k] + V[n]) + cbias)
// UV layout [B,N,2O]: U at [..,0..O), V at [..,O..2O). Writes Xcat slice.
// ---------------------------------------------------------------------------
__global__ __launch_bounds__(256) void k_gather(const float* __restrict__ UV,
                                                const int* __restrict__ idx,
                                                const float* __restrict__ bn,
                                                float* __restrict__ Xcat,
                                                int O2, int O, int coff_out) {
  const int b = blockIdx.z;
  const int og = blockIdx.y * 64;
  const int wave = threadIdx.x >> 6, lane = threadIdx.x & 63;
  const int n = blockIdx.x * 4 + wave;
  const int o = og + lane;
  const int* ip = &idx[(size_t)(b * NPTS + n) * KNN];
  float g = bn[o], be = bn[O + o], mu = bn[2 * O + o], va = bn[3 * O + o];
  float a = g / sqrtf(va + BN_EPS);
  float cb = be - mu * a;
  float vmax = -3.4e38f, vmin = 3.4e38f;
#pragma unroll
  for (int k = 0; k < KNN; ++k) {
    int jn = ip[k];
    float v = UV[(size_t)(b * NPTS + jn) * O2 + o];
    vmax = fmaxf(vmax, v);
    vmin = fminf(vmin, v);
  }
  float Vc = UV[(size_t)(b * NPTS + n) * O2 + O + o];
  float M = ((a >= 0.f) ? vmax : vmin) + Vc;
  float z = fmaf(a, M, cb);
  Xcat[(size_t)(b * NPTS + n) * 512 + coff_out + o] = fmaxf(z, 0.2f * z);
}

// ---------------------------------------------------------------------------
// final BN + leaky + transpose [B,N,512] -> [B,512,N]
// ---------------------------------------------------------------------------
__global__ __launch_bounds__(256) void k_out(const float* __restrict__ Y,
                                             const float* __restrict__ bn,
                                             float* __restrict__ out) {
  int n = blockIdx.x * 256 + threadIdx.x;
  int o = blockIdx.y;
  int b = blockIdx.z;
  float g = bn[o], be = bn[512 + o], mu = bn[1024 + o], va = bn[1536 + o];
  float a = g / sqrtf(va + BN_EPS);
  float cb = be - mu * a;
  float y = Y[(size_t)(b * NPTS + n) * 512 + o];
  float z = fmaf(a, y, cb);
  out[(size_t)(b * 512 + o) * NPTS + n] = fmaxf(z, 0.2f * z);
}

// ---------------------------------------------------------------------------
extern "C" void kernel_launch(void* const* d_in, const int* in_sizes, int n_in,
                              void* d_out, int out_size, void* d_ws,
                              size_t ws_size, hipStream_t stream) {
  const float* x  = (const float*)d_in[0];
  const float* W1 = (const float*)d_in[1];
  const float* W2 = (const float*)d_in[2];
  const float* W3 = (const float*)d_in[3];
  const float* W4 = (const float*)d_in[4];
  const float* W5 = (const float*)d_in[5];
  const float* bn1 = (const float*)d_in[6];
  const float* bn2 = (const float*)d_in[7];
  const float* bn3 = (const float*)d_in[8];
  const float* bn4 = (const float*)d_in[9];
  const float* bn5 = (const float*)d_in[10];
  float* out = (float*)d_out;

  // workspace layout (floats); total ~17.3M floats (~69 MB)
  float* f    = (float*)d_ws;
  float* xt   = f;                        // [B,N,4]        65536
  float* nrm  = f + 65536;                // [B,N]          16384
  int*   idx  = (int*)(f + 81920);        // [B,N,20] int   327680
  float* Xcat = f + 409600;               // [B,N,512]      8388608
  float* UV   = f + 8798208;              // [B,N,512] max  8388608
  float* A2   = f + 17186816;             // [512,128] max  65536

  k_xt<<<64, 256, 0, stream>>>(x, xt, nrm);

  // ---- EdgeConv 1: C=3(pad 4), O=64 ----
  k_prep<<<1, 256, 0, stream>>>(W1, A2, 64, 3, 4);
  k_knn<4><<<dim3(512, 2), 256, 0, stream>>>(xt, nrm, 4, 0, idx);
  k_gemm<<<dim3(128, 2, 2), 256, 0, stream>>>(A2, xt, UV, 4, 0, 4, 128);
  k_gather<<<dim3(2048, 1, 2), 256, 0, stream>>>(UV, idx, bn1, Xcat, 128, 64, 0);

  // ---- EdgeConv 2: C=64, O=64 ----
  k_norms<<<64, 256, 0, stream>>>(Xcat, 512, 0, 64, nrm);
  k_prep<<<16, 256, 0, stream>>>(W2, A2, 64, 64, 64);
  k_knn<64><<<dim3(512, 2), 256, 0, stream>>>(Xcat, nrm, 512, 0, idx);
  k_gemm<<<dim3(128, 2, 2), 256, 0, stream>>>(A2, Xcat, UV, 512, 0, 64, 128);
  k_gather<<<dim3(2048, 1, 2), 256, 0, stream>>>(UV, idx, bn2, Xcat, 128, 64, 64);

  // ---- EdgeConv 3: C=64, O=128 ----
  k_norms<<<64, 256, 0, stream>>>(Xcat, 512, 64, 64, nrm);
  k_prep<<<32, 256, 0, stream>>>(W3, A2, 128, 64, 64);
  k_knn<64><<<dim3(512, 2), 256, 0, stream>>>(Xcat, nrm, 512, 64, idx);
  k_gemm<<<dim3(128, 4, 2), 256, 0, stream>>>(A2, Xcat, UV, 512, 64, 64, 256);
  k_gather<<<dim3(2048, 2, 2), 256, 0, stream>>>(UV, idx, bn3, Xcat, 256, 128, 128);

  // ---- EdgeConv 4: C=128, O=256 ----
  k_norms<<<64, 256, 0, stream>>>(Xcat, 512, 128, 128, nrm);
  k_prep<<<128, 256, 0, stream>>>(W4, A2, 256, 128, 128);
  k_knn<128><<<dim3(512, 2), 256, 0, stream>>>(Xcat, nrm, 512, 128, idx);
  k_gemm<<<dim3(128, 8, 2), 256, 0, stream>>>(A2, Xcat, UV, 512, 128, 128, 512);
  k_gather<<<dim3(2048, 4, 2), 256, 0, stream>>>(UV, idx, bn4, Xcat, 512, 256, 256);

  // ---- conv5 + BN + leaky, output [B,512,N] ----
  k_gemm<<<dim3(128, 8, 2), 256, 0, stream>>>(W5, Xcat, UV, 512, 0, 512, 512);
  k_out<<<dim3(32, 512, 2), 256, 0, stream>>>(UV, bn5, out);
}

// Round 2
// 4766.573 us; speedup vs baseline: 2.5512x; 2.5512x over previous
//
#include <hip/hip_runtime.h>
#include <stdint.h>

#define NPTS 8192
#define BATCH 2
#define KNN 20
#define BN_EPS 1e-5f

// ---------------------------------------------------------------------------
// transpose x [B,3,N] -> xt [B,N,4] (pad 4th chan with 0) + squared norms
// ---------------------------------------------------------------------------
__global__ __launch_bounds__(256) void k_xt(const float* __restrict__ x,
                                            float* __restrict__ xt,
                                            float* __restrict__ nrm) {
  int i = blockIdx.x * 256 + threadIdx.x;          // over B*N
  int b = i / NPTS, n = i % NPTS;
  float x0 = x[((size_t)b * 3 + 0) * NPTS + n];
  float x1 = x[((size_t)b * 3 + 1) * NPTS + n];
  float x2 = x[((size_t)b * 3 + 2) * NPTS + n];
  float4 v = make_float4(x0, x1, x2, 0.f);
  reinterpret_cast<float4*>(xt)[i] = v;
  // mimic np.sum(x*x) order: ((x0^2 + x1^2) + x2^2), no fma
  float s0 = x0 * x0, s1 = x1 * x1, s2 = x2 * x2;
  nrm[i] = (s0 + s1) + s2;
}

// ---------------------------------------------------------------------------
// squared norms of a channel-slice of Xcat: nrm[b*N+n] = sum_c X[(bN+n)*S+coff+c]^2
// ---------------------------------------------------------------------------
__global__ __launch_bounds__(256) void k_norms(const float* __restrict__ X,
                                               int S, int coff, int C,
                                               float* __restrict__ nrm) {
  int i = blockIdx.x * 256 + threadIdx.x;          // over B*N
  const float4* p = reinterpret_cast<const float4*>(&X[(size_t)i * S + coff]);
  float s = 0.f;
  for (int c4 = 0; c4 < (C >> 2); ++c4) {
    float4 v = p[c4];
    s = fmaf(v.x, v.x, s); s = fmaf(v.y, v.y, s);
    s = fmaf(v.z, v.z, s); s = fmaf(v.w, v.w, s);
  }
  nrm[i] = s;
}

// ---------------------------------------------------------------------------
// build stacked weights A2[2O][Cpad]: rows 0..O-1 = Wn, rows O..2O-1 = Wc-Wn
// (zero-pad c >= Creal; W is [O][2*Creal] row-major)
// ---------------------------------------------------------------------------
__global__ __launch_bounds__(256) void k_prep(const float* __restrict__ W,
                                              float* __restrict__ A2,
                                              int O, int Creal, int Cpad) {
  int i = blockIdx.x * 256 + threadIdx.x;
  if (i >= O * Cpad) return;
  int o = i / Cpad, c = i % Cpad;
  float wn = (c < Creal) ? W[(size_t)o * 2 * Creal + c] : 0.f;
  float wc = (c < Creal) ? W[(size_t)o * 2 * Creal + Creal + c] : 0.f;
  A2[(size_t)o * Cpad + c] = wn;
  A2[(size_t)(O + o) * Cpad + c] = wc - wn;
}

// ---------------------------------------------------------------------------
// KNN: for each row i, indices of the 20 smallest (xx_j - (2*dot - xx_i)),
// ties broken by smaller j (== jax.lax.top_k stable semantics on -dist^2).
// Block = 256 thr (4 waves) handles 16 rows; wave w owns rows [4w,4w+4),
// scans ALL j with lane = j-within-tile.
//
// Loop nest is c4-outer / row-inner, CHUNKED by 4 with `#pragma unroll 1`
// on the chunk loop: exactly 4 float4 xj loads (16 VGPRs) in flight.
// (Full unroll let the scheduler hoist all 32 loads -> 256 VGPR + scratch
// spill, 165 MB WRITE_SIZE, 8x regression.  Round-0's row-outer variant
// rematerialized loads instead -> 3.4x VALU bloat.  This bounds both.)
// Accumulation order per row unchanged (ascending c4, x/y/z/w into a[r][0..3],
// then (a0+a1)+(a2+a3)) -> distances bitwise identical to the passing kernel.
// 16 rows/block -> 1024 blocks -> 4 blocks/CU for latency hiding.
// ---------------------------------------------------------------------------
template <int C>
__global__ __launch_bounds__(256) void k_knn(const float* __restrict__ X,
                                             const float* __restrict__ nrm,
                                             int S, int coff,
                                             int* __restrict__ idxout) {
  constexpr int C4 = C / 4;
  constexpr int CH = (C4 < 4) ? C4 : 4;    // c4 chunk size
  constexpr int ROWS = 16;                 // rows per block, 4 per wave
  __shared__ __align__(16) float s_xi[ROWS * C];
  __shared__ float s_ni[ROWS];
  __shared__ unsigned long long s_list[ROWS * KNN];

  const int b = blockIdx.y;
  const int rowbase = blockIdx.x * ROWS;
  const int tid = threadIdx.x, wave = tid >> 6, lane = tid & 63;

  for (int v = tid; v < ROWS * KNN; v += 256) s_list[v] = ~0ull;
  for (int v = tid; v < ROWS * C; v += 256) {
    int r = v / C, c = v % C;
    s_xi[v] = X[(size_t)(b * NPTS + rowbase + r) * S + coff + c];
  }
  if (tid < ROWS) s_ni[tid] = nrm[b * NPTS + rowbase + tid];
  __syncthreads();

  const int r0 = wave * 4;
  for (int jt = 0; jt < NPTS; jt += 64) {
    const int j = jt + lane;
    const float4* xp =
        reinterpret_cast<const float4*>(&X[(size_t)(b * NPTS + j) * S + coff]);
    const float nj = nrm[b * NPTS + j];

    float a[4][4];
#pragma unroll
    for (int r = 0; r < 4; ++r)
      a[r][0] = a[r][1] = a[r][2] = a[r][3] = 0.f;

#pragma unroll 1
    for (int cc = 0; cc < C4; cc += CH) {
      float4 xj[CH];
#pragma unroll
      for (int u = 0; u < CH; ++u) xj[u] = xp[cc + u];   // 4 dwordx4 in flight
#pragma unroll
      for (int u = 0; u < CH; ++u) {
#pragma unroll
        for (int r = 0; r < 4; ++r) {
          float4 v = *reinterpret_cast<const float4*>(
              &s_xi[(r0 + r) * C + 4 * (cc + u)]);       // wave-uniform bcast
          a[r][0] = fmaf(v.x, xj[u].x, a[r][0]);
          a[r][1] = fmaf(v.y, xj[u].y, a[r][1]);
          a[r][2] = fmaf(v.z, xj[u].z, a[r][2]);
          a[r][3] = fmaf(v.w, xj[u].w, a[r][3]);
        }
      }
    }

#pragma unroll
    for (int r = 0; r < 4; ++r) {
      float dot = (a[r][0] + a[r][1]) + (a[r][2] + a[r][3]);
      float t = fmaf(2.f, dot, -s_ni[r0 + r]);     // (-xx_i + 2*dot), ref order
      float d = nj - t;                            // ascending d == descending pd
      unsigned u = __float_as_uint(d);
      u ^= (unsigned)(((int)u) >> 31) | 0x80000000u;   // orderable float
      unsigned long long key = ((unsigned long long)u << 32) | (unsigned)j;

      unsigned long long* lp = &s_list[(r0 + r) * KNN];
      unsigned long long thr = lp[KNN - 1];            // broadcast read
      unsigned long long mask = __ballot(key < thr);
      while (mask) {
        int src = __ffsll((long long)mask) - 1;
        unsigned long long ck = __shfl(key, src);
        unsigned long long e = (lane < KNN) ? lp[lane] : ~0ull;
        unsigned long long ep = __shfl_up(e, 1);
        bool cc2 = ck < e;
        bool cp = (lane > 0) && (ck < ep);
        unsigned long long ne = cp ? ep : (cc2 ? ck : e);
        if (lane < KNN) lp[lane] = ne;
        thr = __shfl(ne, KNN - 1);
        if (lane == src) key = ~0ull;   // consumed
        mask = __ballot(key < thr);
      }
    }
  }
  // each wave owns its rows' lists: write indices (order within k irrelevant)
  if (lane < KNN) {
#pragma unroll
    for (int r = 0; r < 4; ++r)
      idxout[(size_t)(b * NPTS + rowbase + r0 + r) * KNN + lane] =
          (int)(s_list[(r0 + r) * KNN + lane] & 0xffffffffull);
  }
}

// ---------------------------------------------------------------------------
// per-point GEMM: Y[b,n,o] = sum_c A[o*C+c] * X[(b*N+n)*S+coff+c]
// 64 pts x 64 outs per block, K-chunks of 16 staged in LDS, 4x4 per thread.
// ---------------------------------------------------------------------------
__global__ __launch_bounds__(256) void k_gemm(const float* __restrict__ A,
                                              const float* __restrict__ X,
                                              float* __restrict__ Y,
                                              int S, int coff, int C, int O2) {
  __shared__ __align__(16) float sX[16 * 68];
  __shared__ __align__(16) float sA[16 * 68];
  const int b = blockIdx.z;
  const int nb = blockIdx.x * 64;
  const int ob = blockIdx.y * 64;
  const int tid = threadIdx.x, ty = tid >> 4, tx = tid & 15;
  float acc[4][4] = {};

  for (int kc = 0; kc < C; kc += 16) {
#pragma unroll
    for (int t = 0; t < 4; ++t) {
      int v = tid + t * 256;
      int p = v >> 4, k = v & 15;
      float xv = 0.f, av = 0.f;
      if (kc + k < C) {
        xv = X[(size_t)(b * NPTS + nb + p) * S + coff + kc + k];
        av = A[(size_t)(ob + p) * C + kc + k];
      }
      sX[k * 68 + p] = xv;
      sA[k * 68 + p] = av;
    }
    __syncthreads();
#pragma unroll
    for (int kk = 0; kk < 16; ++kk) {
      float4 xa = *reinterpret_cast<const float4*>(&sX[kk * 68 + ty * 4]);
      float4 wb = *reinterpret_cast<const float4*>(&sA[kk * 68 + tx * 4]);
      acc[0][0] = fmaf(xa.x, wb.x, acc[0][0]);
      acc[0][1] = fmaf(xa.x, wb.y, acc[0][1]);
      acc[0][2] = fmaf(xa.x, wb.z, acc[0][2]);
      acc[0][3] = fmaf(xa.x, wb.w, acc[0][3]);
      acc[1][0] = fmaf(xa.y, wb.x, acc[1][0]);
      acc[1][1] = fmaf(xa.y, wb.y, acc[1][1]);
      acc[1][2] = fmaf(xa.y, wb.z, acc[1][2]);
      acc[1][3] = fmaf(xa.y, wb.w, acc[1][3]);
      acc[2][0] = fmaf(xa.z, wb.x, acc[2][0]);
      acc[2][1] = fmaf(xa.z, wb.y, acc[2][1]);
      acc[2][2] = fmaf(xa.z, wb.z, acc[2][2]);
      acc[2][3] = fmaf(xa.z, wb.w, acc[2][3]);
      acc[3][0] = fmaf(xa.w, wb.x, acc[3][0]);
      acc[3][1] = fmaf(xa.w, wb.y, acc[3][1]);
      acc[3][2] = fmaf(xa.w, wb.z, acc[3][2]);
      acc[3][3] = fmaf(xa.w, wb.w, acc[3][3]);
    }
    __syncthreads();
  }
#pragma unroll
  for (int i = 0; i < 4; ++i) {
    float4 st = make_float4(acc[i][0], acc[i][1], acc[i][2], acc[i][3]);
    *reinterpret_cast<float4*>(
        &Y[(size_t)(b * NPTS + nb + ty * 4 + i) * O2 + ob + tx * 4]) = st;
  }
}

// ---------------------------------------------------------------------------
// gather + max-over-k + BN + LeakyReLU (monotone fold):
// out = leaky(a * ((a>=0 ? max_k : min_k) U[idx_k] + V[n]) + cbias)
// UV layout [B,N,2O]: U at [..,0..O), V at [..,O..2O). Writes Xcat slice.
// ---------------------------------------------------------------------------
__global__ __launch_bounds__(256) void k_gather(const float* __restrict__ UV,
                                                const int* __restrict__ idx,
                                                const float* __restrict__ bn,
                                                float* __restrict__ Xcat,
                                                int O2, int O, int coff_out) {
  const int b = blockIdx.z;
  const int og = blockIdx.y * 64;
  const int wave = threadIdx.x >> 6, lane = threadIdx.x & 63;
  const int n = blockIdx.x * 4 + wave;
  const int o = og + lane;
  const int* ip = &idx[(size_t)(b * NPTS + n) * KNN];
  float g = bn[o], be = bn[O + o], mu = bn[2 * O + o], va = bn[3 * O + o];
  float a = g / sqrtf(va + BN_EPS);
  float cb = be - mu * a;
  float vmax = -3.4e38f, vmin = 3.4e38f;
#pragma unroll
  for (int k = 0; k < KNN; ++k) {
    int jn = ip[k];
    float v = UV[(size_t)(b * NPTS + jn) * O2 + o];
    vmax = fmaxf(vmax, v);
    vmin = fminf(vmin, v);
  }
  float Vc = UV[(size_t)(b * NPTS + n) * O2 + O + o];
  float M = ((a >= 0.f) ? vmax : vmin) + Vc;
  float z = fmaf(a, M, cb);
  Xcat[(size_t)(b * NPTS + n) * 512 + coff_out + o] = fmaxf(z, 0.2f * z);
}

// ---------------------------------------------------------------------------
// final BN + leaky + transpose [B,N,512] -> [B,512,N]
// ---------------------------------------------------------------------------
__global__ __launch_bounds__(256) void k_out(const float* __restrict__ Y,
                                             const float* __restrict__ bn,
                                             float* __restrict__ out) {
  int n = blockIdx.x * 256 + threadIdx.x;
  int o = blockIdx.y;
  int b = blockIdx.z;
  float g = bn[o], be = bn[512 + o], mu = bn[1024 + o], va = bn[1536 + o];
  float a = g / sqrtf(va + BN_EPS);
  float cb = be - mu * a;
  float y = Y[(size_t)(b * NPTS + n) * 512 + o];
  float z = fmaf(a, y, cb);
  out[(size_t)(b * 512 + o) * NPTS + n] = fmaxf(z, 0.2f * z);
}

// ---------------------------------------------------------------------------
extern "C" void kernel_launch(void* const* d_in, const int* in_sizes, int n_in,
                              void* d_out, int out_size, void* d_ws,
                              size_t ws_size, hipStream_t stream) {
  const float* x  = (const float*)d_in[0];
  const float* W1 = (const float*)d_in[1];
  const float* W2 = (const float*)d_in[2];
  const float* W3 = (const float*)d_in[3];
  const float* W4 = (const float*)d_in[4];
  const float* W5 = (const float*)d_in[5];
  const float* bn1 = (const float*)d_in[6];
  const float* bn2 = (const float*)d_in[7];
  const float* bn3 = (const float*)d_in[8];
  const float* bn4 = (const float*)d_in[9];
  const float* bn5 = (const float*)d_in[10];
  float* out = (float*)d_out;

  // workspace layout (floats); total ~17.3M floats (~69 MB)
  float* f    = (float*)d_ws;
  float* xt   = f;                        // [B,N,4]        65536
  float* nrm  = f + 65536;                // [B,N]          16384
  int*   idx  = (int*)(f + 81920);        // [B,N,20] int   327680
  float* Xcat = f + 409600;               // [B,N,512]      8388608
  float* UV   = f + 8798208;              // [B,N,512] max  8388608
  float* A2   = f + 17186816;             // [512,128] max  65536

  k_xt<<<64, 256, 0, stream>>>(x, xt, nrm);

  // ---- EdgeConv 1: C=3(pad 4), O=64 ----
  k_prep<<<1, 256, 0, stream>>>(W1, A2, 64, 3, 4);
  k_knn<4><<<dim3(512, 2), 256, 0, stream>>>(xt, nrm, 4, 0, idx);
  k_gemm<<<dim3(128, 2, 2), 256, 0, stream>>>(A2, xt, UV, 4, 0, 4, 128);
  k_gather<<<dim3(2048, 1, 2), 256, 0, stream>>>(UV, idx, bn1, Xcat, 128, 64, 0);

  // ---- EdgeConv 2: C=64, O=64 ----
  k_norms<<<64, 256, 0, stream>>>(Xcat, 512, 0, 64, nrm);
  k_prep<<<16, 256, 0, stream>>>(W2, A2, 64, 64, 64);
  k_knn<64><<<dim3(512, 2), 256, 0, stream>>>(Xcat, nrm, 512, 0, idx);
  k_gemm<<<dim3(128, 2, 2), 256, 0, stream>>>(A2, Xcat, UV, 512, 0, 64, 128);
  k_gather<<<dim3(2048, 1, 2), 256, 0, stream>>>(UV, idx, bn2, Xcat, 128, 64, 64);

  // ---- EdgeConv 3: C=64, O=128 ----
  k_norms<<<64, 256, 0, stream>>>(Xcat, 512, 64, 64, nrm);
  k_prep<<<32, 256, 0, stream>>>(W3, A2, 128, 64, 64);
  k_knn<64><<<dim3(512, 2), 256, 0, stream>>>(Xcat, nrm, 512, 64, idx);
  k_gemm<<<dim3(128, 4, 2), 256, 0, stream>>>(A2, Xcat, UV, 512, 64, 64, 256);
  k_gather<<<dim3(2048, 2, 2), 256, 0, stream>>>(UV, idx, bn3, Xcat, 256, 128, 128);

  // ---- EdgeConv 4: C=128, O=256 ----
  k_norms<<<64, 256, 0, stream>>>(Xcat, 512, 128, 128, nrm);
  k_prep<<<128, 256, 0, stream>>>(W4, A2, 256, 128, 128);
  k_knn<128><<<dim3(512, 2), 256, 0, stream>>>(Xcat, nrm, 512, 128, idx);
  k_gemm<<<dim3(128, 8, 2), 256, 0, stream>>>(A2, Xcat, UV, 512, 128, 128, 512);
  k_gather<<<dim3(2048, 4, 2), 256, 0, stream>>>(UV, idx, bn4, Xcat, 512, 256, 256);

  // ---- conv5 + BN + leaky, output [B,512,N] ----
  k_gemm<<<dim3(128, 8, 2), 256, 0, stream>>>(W5, Xcat, UV, 512, 0, 512, 512);
  k_out<<<dim3(32, 512, 2), 256, 0, stream>>>(UV, bn5, out);
}

// Round 4
// 4185.426 us; speedup vs baseline: 2.9054x; 1.1389x over previous
//
#include <hip/hip_runtime.h>
#include <stdint.h>

#define NPTS 8192
#define BATCH 2
#define KNN 20
#define BN_EPS 1e-5f

// ---------------------------------------------------------------------------
// transpose x [B,3,N] -> xt [B,N,4] (pad 4th chan with 0) + squared norms
// ---------------------------------------------------------------------------
__global__ __launch_bounds__(256) void k_xt(const float* __restrict__ x,
                                            float* __restrict__ xt,
                                            float* __restrict__ nrm) {
  int i = blockIdx.x * 256 + threadIdx.x;          // over B*N
  int b = i / NPTS, n = i % NPTS;
  float x0 = x[((size_t)b * 3 + 0) * NPTS + n];
  float x1 = x[((size_t)b * 3 + 1) * NPTS + n];
  float x2 = x[((size_t)b * 3 + 2) * NPTS + n];
  float4 v = make_float4(x0, x1, x2, 0.f);
  reinterpret_cast<float4*>(xt)[i] = v;
  // mimic np.sum(x*x) order: ((x0^2 + x1^2) + x2^2), no fma
  float s0 = x0 * x0, s1 = x1 * x1, s2 = x2 * x2;
  nrm[i] = (s0 + s1) + s2;
}

// ---------------------------------------------------------------------------
// squared norms of a channel-slice of Xcat: nrm[b*N+n] = sum_c X[(bN+n)*S+coff+c]^2
// ---------------------------------------------------------------------------
__global__ __launch_bounds__(256) void k_norms(const float* __restrict__ X,
                                               int S, int coff, int C,
                                               float* __restrict__ nrm) {
  int i = blockIdx.x * 256 + threadIdx.x;          // over B*N
  const float4* p = reinterpret_cast<const float4*>(&X[(size_t)i * S + coff]);
  float s = 0.f;
  for (int c4 = 0; c4 < (C >> 2); ++c4) {
    float4 v = p[c4];
    s = fmaf(v.x, v.x, s); s = fmaf(v.y, v.y, s);
    s = fmaf(v.z, v.z, s); s = fmaf(v.w, v.w, s);
  }
  nrm[i] = s;
}

// ---------------------------------------------------------------------------
// build stacked weights A2[2O][Cpad]: rows 0..O-1 = Wn, rows O..2O-1 = Wc-Wn
// (zero-pad c >= Creal; W is [O][2*Creal] row-major)
// ---------------------------------------------------------------------------
__global__ __launch_bounds__(256) void k_prep(const float* __restrict__ W,
                                              float* __restrict__ A2,
                                              int O, int Creal, int Cpad) {
  int i = blockIdx.x * 256 + threadIdx.x;
  if (i >= O * Cpad) return;
  int o = i / Cpad, c = i % Cpad;
  float wn = (c < Creal) ? W[(size_t)o * 2 * Creal + c] : 0.f;
  float wc = (c < Creal) ? W[(size_t)o * 2 * Creal + Creal + c] : 0.f;
  A2[(size_t)o * Cpad + c] = wn;
  A2[(size_t)(O + o) * Cpad + c] = wc - wn;
}

// ---------------------------------------------------------------------------
// KNN: for each row i, indices of the 20 smallest (xx_j - (2*dot - xx_i)),
// ties broken by smaller j (== jax.lax.top_k stable semantics on -dist^2).
// Block = 256 thr (4 waves) handles 16 rows; wave w owns rows [4w,4w+4).
//
// v4: j-tiles (64 rows x C) staged in a SINGLE LDS buffer with
// register-held prefetch: cooperative COALESCED global loads of tile t+1
// are issued into registers BEFORE computing tile t (HBM/L2 latency hides
// under the FMAs), then after a barrier the registers are ds_written and a
// second barrier publishes the tile.  (v2: per-lane 2048-B-stride gather =
// 64 cache lines per load instr + 4x redundancy -> L2 congestion, 42k
// cyc/tile vs 1.3k issue.  v3 double-buffered: 76.9 KB static LDS --
// suspect in the container failure; single buffer = 43.8 KB, 3 blocks/CU.)
// LDS layout uses a rotation swizzle slot=(c4+row)&(C4-1) to spread the
// per-lane row reads across banks.  All distance arithmetic (values, FMA
// order, reduction order) unchanged -> bitwise-identical selection.
// ---------------------------------------------------------------------------
template <int C>
__global__ __launch_bounds__(256) void k_knn(const float* __restrict__ X,
                                             const float* __restrict__ nrm,
                                             int S, int coff,
                                             int* __restrict__ idxout) {
  constexpr int C4 = C / 4;
  constexpr int CH = (C4 < 4) ? C4 : 4;      // c4 chunk group size
  constexpr int ROWS = 16;                   // i-rows per block, 4 per wave
  constexpr int NT = NPTS / 64;              // j-tiles
  constexpr int CHUNKS = 64 * C4;            // float4 chunks per j-tile
  constexpr int CPT = (CHUNKS + 255) / 256;  // chunks per thread (8/4/1)

  __shared__ __align__(16) float s_xi[ROWS * C];
  __shared__ float s_ni[ROWS];
  __shared__ unsigned long long s_list[ROWS * KNN];
  __shared__ __align__(16) float s_xj[64 * C];
  __shared__ float s_nj[64];

  const int b = blockIdx.y;
  const int rowbase = blockIdx.x * ROWS;
  const int tid = threadIdx.x, wave = tid >> 6, lane = tid & 63;

  for (int v = tid; v < ROWS * KNN; v += 256) s_list[v] = ~0ull;
  for (int v = tid; v < ROWS * C; v += 256) {
    int r = v / C, c = v % C;
    s_xi[v] = X[(size_t)(b * NPTS + rowbase + r) * S + coff + c];
  }
  if (tid < ROWS) s_ni[tid] = nrm[b * NPTS + rowbase + tid];

  // ---- prologue: stage j-tile 0 ----
#pragma unroll
  for (int q = 0; q < CPT; ++q) {
    int v = q * 256 + tid;
    if (v < CHUNKS) {
      int row = v / C4, s = v % C4;
      float4 ld = *reinterpret_cast<const float4*>(
          &X[(size_t)(b * NPTS + row) * S + coff + 4 * s]);
      int slot = (s + row) & (C4 - 1);
      *reinterpret_cast<float4*>(&s_xj[row * C + 4 * slot]) = ld;
    }
  }
  if (tid < 64) s_nj[tid] = nrm[b * NPTS + tid];
  __syncthreads();

  const int r0 = wave * 4;
  for (int t = 0; t < NT; ++t) {
    const int jt = t * 64;
    const int j = jt + lane;

    // ---- issue coalesced prefetch of tile t+1 into regs (clamped on tail)
    const int tp = (t + 1 < NT) ? t + 1 : NT - 1;
    float4 stg[CPT];
#pragma unroll
    for (int q = 0; q < CPT; ++q) {
      int v = q * 256 + tid;
      if (v < CHUNKS) {
        int row = v / C4, s = v % C4;
        stg[q] = *reinterpret_cast<const float4*>(
            &X[(size_t)(b * NPTS + tp * 64 + row) * S + coff + 4 * s]);
      }
    }
    float njs = (tid < 64) ? nrm[b * NPTS + tp * 64 + tid] : 0.f;

    // ---- compute tile t from LDS ----
    const float nj = s_nj[lane];
    float a[4][4];
#pragma unroll
    for (int r = 0; r < 4; ++r)
      a[r][0] = a[r][1] = a[r][2] = a[r][3] = 0.f;

#pragma unroll 2
    for (int cc = 0; cc < C4; cc += CH) {
      float4 xj[CH];
#pragma unroll
      for (int u = 0; u < CH; ++u) {
        int slot = (cc + u + lane) & (C4 - 1);   // rotation swizzle
        xj[u] = *reinterpret_cast<const float4*>(&s_xj[lane * C + 4 * slot]);
      }
#pragma unroll
      for (int u = 0; u < CH; ++u) {
#pragma unroll
        for (int r = 0; r < 4; ++r) {
          float4 v = *reinterpret_cast<const float4*>(
              &s_xi[(r0 + r) * C + 4 * (cc + u)]);       // wave-uniform bcast
          a[r][0] = fmaf(v.x, xj[u].x, a[r][0]);
          a[r][1] = fmaf(v.y, xj[u].y, a[r][1]);
          a[r][2] = fmaf(v.z, xj[u].z, a[r][2]);
          a[r][3] = fmaf(v.w, xj[u].w, a[r][3]);
        }
      }
    }

#pragma unroll
    for (int r = 0; r < 4; ++r) {
      float dot = (a[r][0] + a[r][1]) + (a[r][2] + a[r][3]);
      float t2 = fmaf(2.f, dot, -s_ni[r0 + r]);    // (-xx_i + 2*dot), ref order
      float d = nj - t2;                           // ascending d == descending pd
      unsigned u = __float_as_uint(d);
      u ^= (unsigned)(((int)u) >> 31) | 0x80000000u;   // orderable float
      unsigned long long key = ((unsigned long long)u << 32) | (unsigned)j;

      unsigned long long* lp = &s_list[(r0 + r) * KNN];
      unsigned long long thr = lp[KNN - 1];            // broadcast read
      unsigned long long mask = __ballot(key < thr);
      while (mask) {
        int src = __ffsll((long long)mask) - 1;
        unsigned long long ck = __shfl(key, src);
        unsigned long long e = (lane < KNN) ? lp[lane] : ~0ull;
        unsigned long long ep = __shfl_up(e, 1);
        bool cc2 = ck < e;
        bool cp = (lane > 0) && (ck < ep);
        unsigned long long ne = cp ? ep : (cc2 ? ck : e);
        if (lane < KNN) lp[lane] = ne;
        thr = __shfl(ne, KNN - 1);
        if (lane == src) key = ~0ull;   // consumed
        mask = __ballot(key < thr);
      }
    }

    // ---- publish prefetched tile (all waves done reading first) ----
    __syncthreads();
#pragma unroll
    for (int q = 0; q < CPT; ++q) {
      int v = q * 256 + tid;
      if (v < CHUNKS) {
        int row = v / C4, s = v % C4;
        int slot = (s + row) & (C4 - 1);
        *reinterpret_cast<float4*>(&s_xj[row * C + 4 * slot]) = stg[q];
      }
    }
    if (tid < 64) s_nj[tid] = njs;
    __syncthreads();
  }

  // each wave owns its rows' lists: write indices (order within k irrelevant)
  if (lane < KNN) {
#pragma unroll
    for (int r = 0; r < 4; ++r)
      idxout[(size_t)(b * NPTS + rowbase + r0 + r) * KNN + lane] =
          (int)(s_list[(r0 + r) * KNN + lane] & 0xffffffffull);
  }
}

// ---------------------------------------------------------------------------
// per-point GEMM: Y[b,n,o] = sum_c A[o*C+c] * X[(b*N+n)*S+coff+c]
// 64 pts x 64 outs per block, K-chunks of 16 staged in LDS, 4x4 per thread.
// ---------------------------------------------------------------------------
__global__ __launch_bounds__(256) void k_gemm(const float* __restrict__ A,
                                              const float* __restrict__ X,
                                              float* __restrict__ Y,
                                              int S, int coff, int C, int O2) {
  __shared__ __align__(16) float sX[16 * 68];
  __shared__ __align__(16) float sA[16 * 68];
  const int b = blockIdx.z;
  const int nb = blockIdx.x * 64;
  const int ob = blockIdx.y * 64;
  const int tid = threadIdx.x, ty = tid >> 4, tx = tid & 15;
  float acc[4][4] = {};

  for (int kc = 0; kc < C; kc += 16) {
#pragma unroll
    for (int t = 0; t < 4; ++t) {
      int v = tid + t * 256;
      int p = v >> 4, k = v & 15;
      float xv = 0.f, av = 0.f;
      if (kc + k < C) {
        xv = X[(size_t)(b * NPTS + nb + p) * S + coff + kc + k];
        av = A[(size_t)(ob + p) * C + kc + k];
      }
      sX[k * 68 + p] = xv;
      sA[k * 68 + p] = av;
    }
    __syncthreads();
#pragma unroll
    for (int kk = 0; kk < 16; ++kk) {
      float4 xa = *reinterpret_cast<const float4*>(&sX[kk * 68 + ty * 4]);
      float4 wb = *reinterpret_cast<const float4*>(&sA[kk * 68 + tx * 4]);
      acc[0][0] = fmaf(xa.x, wb.x, acc[0][0]);
      acc[0][1] = fmaf(xa.x, wb.y, acc[0][1]);
      acc[0][2] = fmaf(xa.x, wb.z, acc[0][2]);
      acc[0][3] = fmaf(xa.x, wb.w, acc[0][3]);
      acc[1][0] = fmaf(xa.y, wb.x, acc[1][0]);
      acc[1][1] = fmaf(xa.y, wb.y, acc[1][1]);
      acc[1][2] = fmaf(xa.y, wb.z, acc[1][2]);
      acc[1][3] = fmaf(xa.y, wb.w, acc[1][3]);
      acc[2][0] = fmaf(xa.z, wb.x, acc[2][0]);
      acc[2][1] = fmaf(xa.z, wb.y, acc[2][1]);
      acc[2][2] = fmaf(xa.z, wb.z, acc[2][2]);
      acc[2][3] = fmaf(xa.z, wb.w, acc[2][3]);
      acc[3][0] = fmaf(xa.w, wb.x, acc[3][0]);
      acc[3][1] = fmaf(xa.w, wb.y, acc[3][1]);
      acc[3][2] = fmaf(xa.w, wb.z, acc[3][2]);
      acc[3][3] = fmaf(xa.w, wb.w, acc[3][3]);
    }
    __syncthreads();
  }
#pragma unroll
  for (int i = 0; i < 4; ++i) {
    float4 st = make_float4(acc[i][0], acc[i][1], acc[i][2], acc[i][3]);
    *reinterpret_cast<float4*>(
        &Y[(size_t)(b * NPTS + nb + ty * 4 + i) * O2 + ob + tx * 4]) = st;
  }
}

// ---------------------------------------------------------------------------
// gather + max-over-k + BN + LeakyReLU (monotone fold):
// out = leaky(a * ((a>=0 ? max_k : min_k) U[idx_k] + V[n]) + cbias)
// UV layout [B,N,2O]: U at [..,0..O), V at [..,O..2O). Writes Xcat slice.
// ---------------------------------------------------------------------------
__global__ __launch_bounds__(256) void k_gather(const float* __restrict__ UV,
                                                const int* __restrict__ idx,
                                                const float* __restrict__ bn,
                                                float* __restrict__ Xcat,
                                                int O2, int O, int coff_out) {
  const int b = blockIdx.z;
  const int og = blockIdx.y * 64;
  const int wave = threadIdx.x >> 6, lane = threadIdx.x & 63;
  const int n = blockIdx.x * 4 + wave;
  const int o = og + lane;
  const int* ip = &idx[(size_t)(b * NPTS + n) * KNN];
  float g = bn[o], be = bn[O + o], mu = bn[2 * O + o], va = bn[3 * O + o];
  float a = g / sqrtf(va + BN_EPS);
  float cb = be - mu * a;
  float vmax = -3.4e38f, vmin = 3.4e38f;
#pragma unroll
  for (int k = 0; k < KNN; ++k) {
    int jn = ip[k];
    float v = UV[(size_t)(b * NPTS + jn) * O2 + o];
    vmax = fmaxf(vmax, v);
    vmin = fminf(vmin, v);
  }
  float Vc = UV[(size_t)(b * NPTS + n) * O2 + O + o];
  float M = ((a >= 0.f) ? vmax : vmin) + Vc;
  float z = fmaf(a, M, cb);
  Xcat[(size_t)(b * NPTS + n) * 512 + coff_out + o] = fmaxf(z, 0.2f * z);
}

// ---------------------------------------------------------------------------
// final BN + leaky + transpose [B,N,512] -> [B,512,N]
// ---------------------------------------------------------------------------
__global__ __launch_bounds__(256) void k_out(const float* __restrict__ Y,
                                             const float* __restrict__ bn,
                                             float* __restrict__ out) {
  int n = blockIdx.x * 256 + threadIdx.x;
  int o = blockIdx.y;
  int b = blockIdx.z;
  float g = bn[o], be = bn[512 + o], mu = bn[1024 + o], va = bn[1536 + o];
  float a = g / sqrtf(va + BN_EPS);
  float cb = be - mu * a;
  float y = Y[(size_t)(b * NPTS + n) * 512 + o];
  float z = fmaf(a, y, cb);
  out[(size_t)(b * 512 + o) * NPTS + n] = fmaxf(z, 0.2f * z);
}

// ---------------------------------------------------------------------------
extern "C" void kernel_launch(void* const* d_in, const int* in_sizes, int n_in,
                              void* d_out, int out_size, void* d_ws,
                              size_t ws_size, hipStream_t stream) {
  const float* x  = (const float*)d_in[0];
  const float* W1 = (const float*)d_in[1];
  const float* W2 = (const float*)d_in[2];
  const float* W3 = (const float*)d_in[3];
  const float* W4 = (const float*)d_in[4];
  const float* W5 = (const float*)d_in[5];
  const float* bn1 = (const float*)d_in[6];
  const float* bn2 = (const float*)d_in[7];
  const float* bn3 = (const float*)d_in[8];
  const float* bn4 = (const float*)d_in[9];
  const float* bn5 = (const float*)d_in[10];
  float* out = (float*)d_out;

  // workspace layout (floats); total ~17.3M floats (~69 MB)
  float* f    = (float*)d_ws;
  float* xt   = f;                        // [B,N,4]        65536
  float* nrm  = f + 65536;                // [B,N]          16384
  int*   idx  = (int*)(f + 81920);        // [B,N,20] int   327680
  float* Xcat = f + 409600;               // [B,N,512]      8388608
  float* UV   = f + 8798208;              // [B,N,512] max  8388608
  float* A2   = f + 17186816;             // [512,128] max  65536

  k_xt<<<64, 256, 0, stream>>>(x, xt, nrm);

  // ---- EdgeConv 1: C=3(pad 4), O=64 ----
  k_prep<<<1, 256, 0, stream>>>(W1, A2, 64, 3, 4);
  k_knn<4><<<dim3(512, 2), 256, 0, stream>>>(xt, nrm, 4, 0, idx);
  k_gemm<<<dim3(128, 2, 2), 256, 0, stream>>>(A2, xt, UV, 4, 0, 4, 128);
  k_gather<<<dim3(2048, 1, 2), 256, 0, stream>>>(UV, idx, bn1, Xcat, 128, 64, 0);

  // ---- EdgeConv 2: C=64, O=64 ----
  k_norms<<<64, 256, 0, stream>>>(Xcat, 512, 0, 64, nrm);
  k_prep<<<16, 256, 0, stream>>>(W2, A2, 64, 64, 64);
  k_knn<64><<<dim3(512, 2), 256, 0, stream>>>(Xcat, nrm, 512, 0, idx);
  k_gemm<<<dim3(128, 2, 2), 256, 0, stream>>>(A2, Xcat, UV, 512, 0, 64, 128);
  k_gather<<<dim3(2048, 1, 2), 256, 0, stream>>>(UV, idx, bn2, Xcat, 128, 64, 64);

  // ---- EdgeConv 3: C=64, O=128 ----
  k_norms<<<64, 256, 0, stream>>>(Xcat, 512, 64, 64, nrm);
  k_prep<<<32, 256, 0, stream>>>(W3, A2, 128, 64, 64);
  k_knn<64><<<dim3(512, 2), 256, 0, stream>>>(Xcat, nrm, 512, 64, idx);
  k_gemm<<<dim3(128, 4, 2), 256, 0, stream>>>(A2, Xcat, UV, 512, 64, 64, 256);
  k_gather<<<dim3(2048, 2, 2), 256, 0, stream>>>(UV, idx, bn3, Xcat, 256, 128, 128);

  // ---- EdgeConv 4: C=128, O=256 ----
  k_norms<<<64, 256, 0, stream>>>(Xcat, 512, 128, 128, nrm);
  k_prep<<<128, 256, 0, stream>>>(W4, A2, 256, 128, 128);
  k_knn<128><<<dim3(512, 2), 256, 0, stream>>>(Xcat, nrm, 512, 128, idx);
  k_gemm<<<dim3(128, 8, 2), 256, 0, stream>>>(A2, Xcat, UV, 512, 128, 128, 512);
  k_gather<<<dim3(2048, 4, 2), 256, 0, stream>>>(UV, idx, bn4, Xcat, 512, 256, 256);

  // ---- conv5 + BN + leaky, output [B,512,N] ----
  k_gemm<<<dim3(128, 8, 2), 256, 0, stream>>>(W5, Xcat, UV, 512, 0, 512, 512);
  k_out<<<dim3(32, 512, 2), 256, 0, stream>>>(UV, bn5, out);
}

// Round 5
// 4096.184 us; speedup vs baseline: 2.9688x; 1.0218x over previous
//
#include <hip/hip_runtime.h>
#include <stdint.h>

#define NPTS 8192
#define BATCH 2
#define KNN 20
#define BN_EPS 1e-5f

// ---------------------------------------------------------------------------
// transpose x [B,3,N] -> xt [B,N,4] (pad 4th chan with 0) + squared norms
// ---------------------------------------------------------------------------
__global__ __launch_bounds__(256) void k_xt(const float* __restrict__ x,
                                            float* __restrict__ xt,
                                            float* __restrict__ nrm) {
  int i = blockIdx.x * 256 + threadIdx.x;          // over B*N
  int b = i / NPTS, n = i % NPTS;
  float x0 = x[((size_t)b * 3 + 0) * NPTS + n];
  float x1 = x[((size_t)b * 3 + 1) * NPTS + n];
  float x2 = x[((size_t)b * 3 + 2) * NPTS + n];
  float4 v = make_float4(x0, x1, x2, 0.f);
  reinterpret_cast<float4*>(xt)[i] = v;
  // mimic np.sum(x*x) order: ((x0^2 + x1^2) + x2^2), no fma
  float s0 = x0 * x0, s1 = x1 * x1, s2 = x2 * x2;
  nrm[i] = (s0 + s1) + s2;
}

// ---------------------------------------------------------------------------
// squared norms of a channel-slice of Xcat: nrm[b*N+n] = sum_c X[(bN+n)*S+coff+c]^2
// ---------------------------------------------------------------------------
__global__ __launch_bounds__(256) void k_norms(const float* __restrict__ X,
                                               int S, int coff, int C,
                                               float* __restrict__ nrm) {
  int i = blockIdx.x * 256 + threadIdx.x;          // over B*N
  const float4* p = reinterpret_cast<const float4*>(&X[(size_t)i * S + coff]);
  float s = 0.f;
  for (int c4 = 0; c4 < (C >> 2); ++c4) {
    float4 v = p[c4];
    s = fmaf(v.x, v.x, s); s = fmaf(v.y, v.y, s);
    s = fmaf(v.z, v.z, s); s = fmaf(v.w, v.w, s);
  }
  nrm[i] = s;
}

// ---------------------------------------------------------------------------
// build stacked weights A2[2O][Cpad]: rows 0..O-1 = Wn, rows O..2O-1 = Wc-Wn
// (zero-pad c >= Creal; W is [O][2*Creal] row-major)
// ---------------------------------------------------------------------------
__global__ __launch_bounds__(256) void k_prep(const float* __restrict__ W,
                                              float* __restrict__ A2,
                                              int O, int Creal, int Cpad) {
  int i = blockIdx.x * 256 + threadIdx.x;
  if (i >= O * Cpad) return;
  int o = i / Cpad, c = i % Cpad;
  float wn = (c < Creal) ? W[(size_t)o * 2 * Creal + c] : 0.f;
  float wc = (c < Creal) ? W[(size_t)o * 2 * Creal + Creal + c] : 0.f;
  A2[(size_t)o * Cpad + c] = wn;
  A2[(size_t)(O + o) * Cpad + c] = wc - wn;
}

// ---------------------------------------------------------------------------
// KNN: for each row i, indices of the 20 smallest (xx_j - (2*dot - xx_i)),
// ties broken by smaller j (== jax.lax.top_k stable semantics on -dist^2).
// Block = 256 thr (4 waves) handles 16 rows; wave w owns rows [4w,4w+4).
//
// v5: same LDS-staged single-buffer pipeline as v4, but the prefetch
// registers (stg) are now live ONLY across the straight-line FMA phase:
//   issue loads(t+1) -> FMAs(t) -> keys[4] -> barrier -> publish -> barrier
//   -> selection(t)
// (v4 kept stg live across the variable-length selection loop; the
// allocator spilled it -> 3.1 GB/dispatch scratch WRITE_SIZE, the wall.)
// __launch_bounds__(256,3): 3 waves/EU target (= the LDS-bound 3 blocks/CU)
// raises the VGPR budget to ~168 so stg register-allocates.
// LDS rotation swizzle slot=(c4+row)&(C4-1) on both write and read sides.
// All distance arithmetic (values, FMA order, reduction order, key packing)
// unchanged -> bitwise-identical selection.
// ---------------------------------------------------------------------------
template <int C>
__global__ __launch_bounds__(256, 3) void k_knn(const float* __restrict__ X,
                                                const float* __restrict__ nrm,
                                                int S, int coff,
                                                int* __restrict__ idxout) {
  constexpr int C4 = C / 4;
  constexpr int CH = (C4 < 4) ? C4 : 4;      // c4 chunk group size
  constexpr int ROWS = 16;                   // i-rows per block, 4 per wave
  constexpr int NT = NPTS / 64;              // j-tiles
  constexpr int CHUNKS = 64 * C4;            // float4 chunks per j-tile
  constexpr int CPT = (CHUNKS + 255) / 256;  // chunks per thread (8/4/1)

  __shared__ __align__(16) float s_xi[ROWS * C];
  __shared__ float s_ni[ROWS];
  __shared__ unsigned long long s_list[ROWS * KNN];
  __shared__ __align__(16) float s_xj[64 * C];
  __shared__ float s_nj[64];

  const int b = blockIdx.y;
  const int rowbase = blockIdx.x * ROWS;
  const int tid = threadIdx.x, wave = tid >> 6, lane = tid & 63;

  for (int v = tid; v < ROWS * KNN; v += 256) s_list[v] = ~0ull;
  for (int v = tid; v < ROWS * C; v += 256) {
    int r = v / C, c = v % C;
    s_xi[v] = X[(size_t)(b * NPTS + rowbase + r) * S + coff + c];
  }
  if (tid < ROWS) s_ni[tid] = nrm[b * NPTS + rowbase + tid];

  // ---- prologue: stage j-tile 0 ----
#pragma unroll
  for (int q = 0; q < CPT; ++q) {
    int v = q * 256 + tid;
    if (v < CHUNKS) {
      int row = v / C4, s = v % C4;
      float4 ld = *reinterpret_cast<const float4*>(
          &X[(size_t)(b * NPTS + row) * S + coff + 4 * s]);
      int slot = (s + row) & (C4 - 1);
      *reinterpret_cast<float4*>(&s_xj[row * C + 4 * slot]) = ld;
    }
  }
  if (tid < 64) s_nj[tid] = nrm[b * NPTS + tid];
  __syncthreads();

  const int r0 = wave * 4;
  for (int t = 0; t < NT; ++t) {
    const int jt = t * 64;
    const int j = jt + lane;

    // ---- issue coalesced prefetch of tile t+1 into regs (clamped on tail)
    const int tp = (t + 1 < NT) ? t + 1 : NT - 1;
    float4 stg[CPT];
#pragma unroll
    for (int q = 0; q < CPT; ++q) {
      int v = q * 256 + tid;
      if (v < CHUNKS) {
        int row = v / C4, s = v % C4;
        stg[q] = *reinterpret_cast<const float4*>(
            &X[(size_t)(b * NPTS + tp * 64 + row) * S + coff + 4 * s]);
      }
    }
    float njs = (tid < 64) ? nrm[b * NPTS + tp * 64 + tid] : 0.f;

    // ---- compute tile t from LDS (load latency hides under these FMAs) ----
    const float nj = s_nj[lane];
    float a[4][4];
#pragma unroll
    for (int r = 0; r < 4; ++r)
      a[r][0] = a[r][1] = a[r][2] = a[r][3] = 0.f;

#pragma unroll 2
    for (int cc = 0; cc < C4; cc += CH) {
      float4 xj[CH];
#pragma unroll
      for (int u = 0; u < CH; ++u) {
        int slot = (cc + u + lane) & (C4 - 1);   // rotation swizzle
        xj[u] = *reinterpret_cast<const float4*>(&s_xj[lane * C + 4 * slot]);
      }
#pragma unroll
      for (int u = 0; u < CH; ++u) {
#pragma unroll
        for (int r = 0; r < 4; ++r) {
          float4 v = *reinterpret_cast<const float4*>(
              &s_xi[(r0 + r) * C + 4 * (cc + u)]);       // wave-uniform bcast
          a[r][0] = fmaf(v.x, xj[u].x, a[r][0]);
          a[r][1] = fmaf(v.y, xj[u].y, a[r][1]);
          a[r][2] = fmaf(v.z, xj[u].z, a[r][2]);
          a[r][3] = fmaf(v.w, xj[u].w, a[r][3]);
        }
      }
    }

    // ---- finalize the 4 keys for this tile (before publishing overwrites)
    unsigned long long keys[4];
#pragma unroll
    for (int r = 0; r < 4; ++r) {
      float dot = (a[r][0] + a[r][1]) + (a[r][2] + a[r][3]);
      float t2 = fmaf(2.f, dot, -s_ni[r0 + r]);    // (-xx_i + 2*dot), ref order
      float d = nj - t2;                           // ascending d == descending pd
      unsigned u = __float_as_uint(d);
      u ^= (unsigned)(((int)u) >> 31) | 0x80000000u;   // orderable float
      keys[r] = ((unsigned long long)u << 32) | (unsigned)j;
    }

    // ---- publish prefetched tile NOW (stg dies here, before selection) ----
    __syncthreads();
#pragma unroll
    for (int q = 0; q < CPT; ++q) {
      int v = q * 256 + tid;
      if (v < CHUNKS) {
        int row = v / C4, s = v % C4;
        int slot = (s + row) & (C4 - 1);
        *reinterpret_cast<float4*>(&s_xj[row * C + 4 * slot]) = stg[q];
      }
    }
    if (tid < 64) s_nj[tid] = njs;
    __syncthreads();

    // ---- top-20 selection for tile t (uses saved keys only) ----
#pragma unroll
    for (int r = 0; r < 4; ++r) {
      unsigned long long key = keys[r];
      unsigned long long* lp = &s_list[(r0 + r) * KNN];
      unsigned long long thr = lp[KNN - 1];            // broadcast read
      unsigned long long mask = __ballot(key < thr);
      while (mask) {
        int src = __ffsll((long long)mask) - 1;
        unsigned long long ck = __shfl(key, src);
        unsigned long long e = (lane < KNN) ? lp[lane] : ~0ull;
        unsigned long long ep = __shfl_up(e, 1);
        bool cc2 = ck < e;
        bool cp = (lane > 0) && (ck < ep);
        unsigned long long ne = cp ? ep : (cc2 ? ck : e);
        if (lane < KNN) lp[lane] = ne;
        thr = __shfl(ne, KNN - 1);
        if (lane == src) key = ~0ull;   // consumed
        mask = __ballot(key < thr);
      }
    }
  }

  // each wave owns its rows' lists: write indices (order within k irrelevant)
  if (lane < KNN) {
#pragma unroll
    for (int r = 0; r < 4; ++r)
      idxout[(size_t)(b * NPTS + rowbase + r0 + r) * KNN + lane] =
          (int)(s_list[(r0 + r) * KNN + lane] & 0xffffffffull);
  }
}

// ---------------------------------------------------------------------------
// per-point GEMM: Y[b,n,o] = sum_c A[o*C+c] * X[(b*N+n)*S+coff+c]
// 64 pts x 64 outs per block, K-chunks of 16 staged in LDS, 4x4 per thread.
// ---------------------------------------------------------------------------
__global__ __launch_bounds__(256) void k_gemm(const float* __restrict__ A,
                                              const float* __restrict__ X,
                                              float* __restrict__ Y,
                                              int S, int coff, int C, int O2) {
  __shared__ __align__(16) float sX[16 * 68];
  __shared__ __align__(16) float sA[16 * 68];
  const int b = blockIdx.z;
  const int nb = blockIdx.x * 64;
  const int ob = blockIdx.y * 64;
  const int tid = threadIdx.x, ty = tid >> 4, tx = tid & 15;
  float acc[4][4] = {};

  for (int kc = 0; kc < C; kc += 16) {
#pragma unroll
    for (int t = 0; t < 4; ++t) {
      int v = tid + t * 256;
      int p = v >> 4, k = v & 15;
      float xv = 0.f, av = 0.f;
      if (kc + k < C) {
        xv = X[(size_t)(b * NPTS + nb + p) * S + coff + kc + k];
        av = A[(size_t)(ob + p) * C + kc + k];
      }
      sX[k * 68 + p] = xv;
      sA[k * 68 + p] = av;
    }
    __syncthreads();
#pragma unroll
    for (int kk = 0; kk < 16; ++kk) {
      float4 xa = *reinterpret_cast<const float4*>(&sX[kk * 68 + ty * 4]);
      float4 wb = *reinterpret_cast<const float4*>(&sA[kk * 68 + tx * 4]);
      acc[0][0] = fmaf(xa.x, wb.x, acc[0][0]);
      acc[0][1] = fmaf(xa.x, wb.y, acc[0][1]);
      acc[0][2] = fmaf(xa.x, wb.z, acc[0][2]);
      acc[0][3] = fmaf(xa.x, wb.w, acc[0][3]);
      acc[1][0] = fmaf(xa.y, wb.x, acc[1][0]);
      acc[1][1] = fmaf(xa.y, wb.y, acc[1][1]);
      acc[1][2] = fmaf(xa.y, wb.z, acc[1][2]);
      acc[1][3] = fmaf(xa.y, wb.w, acc[1][3]);
      acc[2][0] = fmaf(xa.z, wb.x, acc[2][0]);
      acc[2][1] = fmaf(xa.z, wb.y, acc[2][1]);
      acc[2][2] = fmaf(xa.z, wb.z, acc[2][2]);
      acc[2][3] = fmaf(xa.z, wb.w, acc[2][3]);
      acc[3][0] = fmaf(xa.w, wb.x, acc[3][0]);
      acc[3][1] = fmaf(xa.w, wb.y, acc[3][1]);
      acc[3][2] = fmaf(xa.w, wb.z, acc[3][2]);
      acc[3][3] = fmaf(xa.w, wb.w, acc[3][3]);
    }
    __syncthreads();
  }
#pragma unroll
  for (int i = 0; i < 4; ++i) {
    float4 st = make_float4(acc[i][0], acc[i][1], acc[i][2], acc[i][3]);
    *reinterpret_cast<float4*>(
        &Y[(size_t)(b * NPTS + nb + ty * 4 + i) * O2 + ob + tx * 4]) = st;
  }
}

// ---------------------------------------------------------------------------
// gather + max-over-k + BN + LeakyReLU (monotone fold):
// out = leaky(a * ((a>=0 ? max_k : min_k) U[idx_k] + V[n]) + cbias)
// UV layout [B,N,2O]: U at [..,0..O), V at [..,O..2O). Writes Xcat slice.
// ---------------------------------------------------------------------------
__global__ __launch_bounds__(256) void k_gather(const float* __restrict__ UV,
                                                const int* __restrict__ idx,
                                                const float* __restrict__ bn,
                                                float* __restrict__ Xcat,
                                                int O2, int O, int coff_out) {
  const int b = blockIdx.z;
  const int og = blockIdx.y * 64;
  const int wave = threadIdx.x >> 6, lane = threadIdx.x & 63;
  const int n = blockIdx.x * 4 + wave;
  const int o = og + lane;
  const int* ip = &idx[(size_t)(b * NPTS + n) * KNN];
  float g = bn[o], be = bn[O + o], mu = bn[2 * O + o], va = bn[3 * O + o];
  float a = g / sqrtf(va + BN_EPS);
  float cb = be - mu * a;
  float vmax = -3.4e38f, vmin = 3.4e38f;
#pragma unroll
  for (int k = 0; k < KNN; ++k) {
    int jn = ip[k];
    float v = UV[(size_t)(b * NPTS + jn) * O2 + o];
    vmax = fmaxf(vmax, v);
    vmin = fminf(vmin, v);
  }
  float Vc = UV[(size_t)(b * NPTS + n) * O2 + O + o];
  float M = ((a >= 0.f) ? vmax : vmin) + Vc;
  float z = fmaf(a, M, cb);
  Xcat[(size_t)(b * NPTS + n) * 512 + coff_out + o] = fmaxf(z, 0.2f * z);
}

// ---------------------------------------------------------------------------
// final BN + leaky + transpose [B,N,512] -> [B,512,N]
// ---------------------------------------------------------------------------
__global__ __launch_bounds__(256) void k_out(const float* __restrict__ Y,
                                             const float* __restrict__ bn,
                                             float* __restrict__ out) {
  int n = blockIdx.x * 256 + threadIdx.x;
  int o = blockIdx.y;
  int b = blockIdx.z;
  float g = bn[o], be = bn[512 + o], mu = bn[1024 + o], va = bn[1536 + o];
  float a = g / sqrtf(va + BN_EPS);
  float cb = be - mu * a;
  float y = Y[(size_t)(b * NPTS + n) * 512 + o];
  float z = fmaf(a, y, cb);
  out[(size_t)(b * 512 + o) * NPTS + n] = fmaxf(z, 0.2f * z);
}

// ---------------------------------------------------------------------------
extern "C" void kernel_launch(void* const* d_in, const int* in_sizes, int n_in,
                              void* d_out, int out_size, void* d_ws,
                              size_t ws_size, hipStream_t stream) {
  const float* x  = (const float*)d_in[0];
  const float* W1 = (const float*)d_in[1];
  const float* W2 = (const float*)d_in[2];
  const float* W3 = (const float*)d_in[3];
  const float* W4 = (const float*)d_in[4];
  const float* W5 = (const float*)d_in[5];
  const float* bn1 = (const float*)d_in[6];
  const float* bn2 = (const float*)d_in[7];
  const float* bn3 = (const float*)d_in[8];
  const float* bn4 = (const float*)d_in[9];
  const float* bn5 = (const float*)d_in[10];
  float* out = (float*)d_out;

  // workspace layout (floats); total ~17.3M floats (~69 MB)
  float* f    = (float*)d_ws;
  float* xt   = f;                        // [B,N,4]        65536
  float* nrm  = f + 65536;                // [B,N]          16384
  int*   idx  = (int*)(f + 81920);        // [B,N,20] int   327680
  float* Xcat = f + 409600;               // [B,N,512]      8388608
  float* UV   = f + 8798208;              // [B,N,512] max  8388608
  float* A2   = f + 17186816;             // [512,128] max  65536

  k_xt<<<64, 256, 0, stream>>>(x, xt, nrm);

  // ---- EdgeConv 1: C=3(pad 4), O=64 ----
  k_prep<<<1, 256, 0, stream>>>(W1, A2, 64, 3, 4);
  k_knn<4><<<dim3(512, 2), 256, 0, stream>>>(xt, nrm, 4, 0, idx);
  k_gemm<<<dim3(128, 2, 2), 256, 0, stream>>>(A2, xt, UV, 4, 0, 4, 128);
  k_gather<<<dim3(2048, 1, 2), 256, 0, stream>>>(UV, idx, bn1, Xcat, 128, 64, 0);

  // ---- EdgeConv 2: C=64, O=64 ----
  k_norms<<<64, 256, 0, stream>>>(Xcat, 512, 0, 64, nrm);
  k_prep<<<16, 256, 0, stream>>>(W2, A2, 64, 64, 64);
  k_knn<64><<<dim3(512, 2), 256, 0, stream>>>(Xcat, nrm, 512, 0, idx);
  k_gemm<<<dim3(128, 2, 2), 256, 0, stream>>>(A2, Xcat, UV, 512, 0, 64, 128);
  k_gather<<<dim3(2048, 1, 2), 256, 0, stream>>>(UV, idx, bn2, Xcat, 128, 64, 64);

  // ---- EdgeConv 3: C=64, O=128 ----
  k_norms<<<64, 256, 0, stream>>>(Xcat, 512, 64, 64, nrm);
  k_prep<<<32, 256, 0, stream>>>(W3, A2, 128, 64, 64);
  k_knn<64><<<dim3(512, 2), 256, 0, stream>>>(Xcat, nrm, 512, 64, idx);
  k_gemm<<<dim3(128, 4, 2), 256, 0, stream>>>(A2, Xcat, UV, 512, 64, 64, 256);
  k_gather<<<dim3(2048, 2, 2), 256, 0, stream>>>(UV, idx, bn3, Xcat, 256, 128, 128);

  // ---- EdgeConv 4: C=128, O=256 ----
  k_norms<<<64, 256, 0, stream>>>(Xcat, 512, 128, 128, nrm);
  k_prep<<<128, 256, 0, stream>>>(W4, A2, 256, 128, 128);
  k_knn<128><<<dim3(512, 2), 256, 0, stream>>>(Xcat, nrm, 512, 128, idx);
  k_gemm<<<dim3(128, 8, 2), 256, 0, stream>>>(A2, Xcat, UV, 512, 128, 128, 512);
  k_gather<<<dim3(2048, 4, 2), 256, 0, stream>>>(UV, idx, bn4, Xcat, 512, 256, 256);

  // ---- conv5 + BN + leaky, output [B,512,N] ----
  k_gemm<<<dim3(128, 8, 2), 256, 0, stream>>>(W5, Xcat, UV, 512, 0, 512, 512);
  k_out<<<dim3(32, 512, 2), 256, 0, stream>>>(UV, bn5, out);
}